// Round 9
// baseline (1200.864 us; speedup 1.0000x reference)
//
#include <hip/hip_runtime.h>
#include <hip/hip_bf16.h>
#include <cstdint>
#include <cmath>

// ============ ROUND 8: INSTRUMENTATION BUILD ============
// proj_gemm body x10, scores body x4 (idempotent reps) so both dispatches
// exceed the ~330us harness poison-fills and surface in the top-5 with
// real counters. Revert REPS to 1 after reading the split.
#define PROJ_REPS 10
#define SCORES_REPS 4

typedef __bf16 bf16_t;
typedef __attribute__((ext_vector_type(8))) bf16_t bf16x8;
typedef __attribute__((ext_vector_type(4))) float f32x4;

#define AS_GLOBAL(p) ((const __attribute__((address_space(1))) void*)(p))
#define AS_LDS(p)    ((__attribute__((address_space(3))) void*)(p))

// fp32 -> bf16 RTNE
__device__ __forceinline__ unsigned short f2bf(float f) {
  unsigned u = __builtin_bit_cast(unsigned, f);
  u += 0x7FFFu + ((u >> 16) & 1u);
  return (unsigned short)(u >> 16);
}

// ---------------- fused convert fp32 -> bf16 (x4 vectorized) ----------------
#define N4_X  2097152
#define N4_W  1048576
__global__ void cvt3_kernel(const float* __restrict__ x, const float* __restrict__ wq,
                            const float* __restrict__ wk, ushort4* __restrict__ xb4,
                            ushort4* __restrict__ wb4, float scale) {
  int i = blockIdx.x * blockDim.x + threadIdx.x;
  int stride = gridDim.x * blockDim.x;
  for (; i < N4_X + 2 * N4_W; i += stride) {
    const float4* src;
    ushort4* dst;
    float sc = 1.0f;
    if (i < N4_X) {
      src = reinterpret_cast<const float4*>(x) + i;
      dst = xb4 + i;
    } else if (i < N4_X + N4_W) {
      src = reinterpret_cast<const float4*>(wq) + (i - N4_X);
      dst = wb4 + (i - N4_X);
      sc = scale;
    } else {
      src = reinterpret_cast<const float4*>(wk) + (i - N4_X - N4_W);
      dst = wb4 + (i - N4_X);
    }
    float4 v = *src;
    ushort4 o;
    o.x = f2bf(v.x * sc);
    o.y = f2bf(v.y * sc);
    o.z = f2bf(v.z * sc);
    o.w = f2bf(v.w * sc);
    *dst = o;
  }
}

// ================= projection GEMM: 256x256 tile, 8-phase schedule (R6-proven) =================
#define PM 4096
#define PN 4096
#define PK 2048
#define PNT 32   // K tiles

template<int VM> __device__ __forceinline__ void waitcnt_vm() {
  if constexpr (VM == 0)  asm volatile("s_waitcnt vmcnt(0)" ::: "memory");
  else if constexpr (VM == 2)  asm volatile("s_waitcnt vmcnt(2)" ::: "memory");
  else if constexpr (VM == 4)  asm volatile("s_waitcnt vmcnt(4)" ::: "memory");
  else if constexpr (VM == 6)  asm volatile("s_waitcnt vmcnt(6)" ::: "memory");
  else if constexpr (VM == 8)  asm volatile("s_waitcnt vmcnt(8)" ::: "memory");
  else if constexpr (VM == 10) asm volatile("s_waitcnt vmcnt(10)" ::: "memory");
  // VM < 0: no wait
}

// stage one 128x64 half-tile (16 KB): 2 x global_load_lds(16B) per thread
__device__ __forceinline__ void stage_half(const unsigned short* A, const unsigned short* B,
                                           int m0, int n0, int H, int wave, int lane,
                                           char* lds) {
  int tile = H >> 2;
  int mat  = H & 1;          // 0=A, 1=B
  int half = (H >> 1) & 1;
  int buf  = tile & 1;
  const unsigned short* src = mat ? B : A;
  int base0 = mat ? n0 : m0;
  char* hbase = lds + (((buf * 2 + mat) * 2 + half) * 16384);
  #pragma unroll
  for (int l = 0; l < 2; ++l) {
    int o = l * 8192 + wave * 1024 + lane * 16;
    int row = o >> 7;                  // 128B rows (BK=64 bf16)
    int c = o & 127;
    int csrc = c ^ ((row & 7) << 4);   // pre-swizzled global source
    const char* g = (const char*)(src + (size_t)(base0 + half * 128 + row) * PK)
                    + tile * 128 + csrc;
    __builtin_amdgcn_global_load_lds(AS_GLOBAL(g), AS_LDS(hbase + l * 8192 + wave * 1024),
                                     16, 0, 0);
  }
}

template<int Q, int VM>
__device__ __forceinline__ void phase(const unsigned short* A, const unsigned short* B,
                                      int m0, int n0, int T, int wave, int lane,
                                      int wm, int wn, char* lds, f32x4 (&acc)[8][4]) {
  constexpr int gm = Q >> 1, gn = Q & 1;
  const int buf = T & 1;
  const char* Ab = lds + (((buf * 2 + 0) * 2 + gm) * 16384);
  const char* Bb = lds + (((buf * 2 + 1) * 2 + gn) * 16384);

  bf16x8 av[4][2], bv[2][2];
  #pragma unroll
  for (int j = 0; j < 4; ++j) {
    int row = j * 32 + wm * 16 + (lane & 15);
    #pragma unroll
    for (int ks = 0; ks < 2; ++ks) {
      int kb = ks * 64 + (lane >> 4) * 16;
      av[j][ks] = *(const bf16x8*)(Ab + row * 128 + (kb ^ ((row & 7) << 4)));
    }
  }
  #pragma unroll
  for (int i = 0; i < 2; ++i) {
    int row = i * 64 + wn * 16 + (lane & 15);
    #pragma unroll
    for (int ks = 0; ks < 2; ++ks) {
      int kb = ks * 64 + (lane >> 4) * 16;
      bv[i][ks] = *(const bf16x8*)(Bb + row * 128 + (kb ^ ((row & 7) << 4)));
    }
  }

  int H = 4 * T + Q + 6;
  if (H < 4 * PNT) stage_half(A, B, m0, n0, H, wave, lane, lds);

  waitcnt_vm<VM>();
  asm volatile("s_barrier" ::: "memory");
  asm volatile("s_waitcnt lgkmcnt(0)" ::: "memory");
  __builtin_amdgcn_sched_barrier(0);

  __builtin_amdgcn_s_setprio(1);
  #pragma unroll
  for (int j = 0; j < 4; ++j)
    #pragma unroll
    for (int i = 0; i < 2; ++i)
      #pragma unroll
      for (int ks = 0; ks < 2; ++ks)
        acc[gm * 4 + j][gn * 2 + i] =
          __builtin_amdgcn_mfma_f32_16x16x32_bf16(av[j][ks], bv[i][ks],
                                                  acc[gm * 4 + j][gn * 2 + i], 0, 0, 0);
  __builtin_amdgcn_s_setprio(0);
  asm volatile("s_barrier" ::: "memory");
}

__global__ __launch_bounds__(512, 2) void proj_gemm(const unsigned short* __restrict__ A,
                                                    const unsigned short* __restrict__ Bm,
                                                    unsigned short* __restrict__ C) {
  __shared__ __align__(16) char lds[131072];
  const int tid = threadIdx.x;
  const int wave = tid >> 6, lane = tid & 63;
  const int wm = wave >> 2, wn = wave & 3;
  const int m0 = blockIdx.y * 256;
  const int n0 = blockIdx.x * 256;

  #pragma unroll 1
  for (int rep = 0; rep < PROJ_REPS; ++rep) {
    f32x4 acc[8][4] = {};

    #pragma unroll
    for (int h = 0; h < 6; ++h) stage_half(A, Bm, m0, n0, h, wave, lane, lds);
    waitcnt_vm<8>();
    asm volatile("s_barrier" ::: "memory");

    for (int T = 0; T < PNT - 2; ++T) {
      phase<0, 6>(A, Bm, m0, n0, T, wave, lane, wm, wn, lds, acc);
      phase<1, 10>(A, Bm, m0, n0, T, wave, lane, wm, wn, lds, acc);
      phase<2, 10>(A, Bm, m0, n0, T, wave, lane, wm, wn, lds, acc);
      phase<3, 8>(A, Bm, m0, n0, T, wave, lane, wm, wn, lds, acc);
    }
    phase<0, 6>(A, Bm, m0, n0, PNT - 2, wave, lane, wm, wn, lds, acc);
    phase<1, 10>(A, Bm, m0, n0, PNT - 2, wave, lane, wm, wn, lds, acc);
    phase<2, 8>(A, Bm, m0, n0, PNT - 2, wave, lane, wm, wn, lds, acc);
    phase<3, 4>(A, Bm, m0, n0, PNT - 2, wave, lane, wm, wn, lds, acc);
    phase<0, 0>(A, Bm, m0, n0, PNT - 1, wave, lane, wm, wn, lds, acc);
    phase<1, -1>(A, Bm, m0, n0, PNT - 1, wave, lane, wm, wn, lds, acc);
    phase<2, -1>(A, Bm, m0, n0, PNT - 1, wave, lane, wm, wn, lds, acc);
    phase<3, -1>(A, Bm, m0, n0, PNT - 1, wave, lane, wm, wn, lds, acc);

    #pragma unroll
    for (int f = 0; f < 8; ++f) {
      int rbase = m0 + (f >> 2) * 128 + (f & 3) * 32 + wm * 16 + (lane >> 4) * 4;
      #pragma unroll
      for (int nf = 0; nf < 4; ++nf) {
        int col = n0 + (nf >> 1) * 128 + (nf & 1) * 64 + wn * 16 + (lane & 15);
        #pragma unroll
        for (int r = 0; r < 4; ++r)
          C[(size_t)(rbase + r) * PN + col] = f2bf(acc[f][nf][r]);
      }
    }
    // rep boundary: all waves past final phase barriers; epilogue stores are
    // idempotent; next rep re-stages from half 0.
    asm volatile("s_barrier" ::: "memory");
  }
}

// ---------------- scores kernel (R6-proven 128x128): persistent-Q, streaming-K ----------------
__global__ __launch_bounds__(256) void scores_kernel(const unsigned short* __restrict__ qk,
                                                     float* __restrict__ out2) {
  __shared__ unsigned short Ks[2][128 * 128];
  const int tid = threadIdx.x;
  const int wave = tid >> 6, lane = tid & 63;
  const int qtile = blockIdx.x;
  const int bh = blockIdx.y;
  const int b = bh >> 4, h = bh & 15;
  const int wr = wave >> 1, wc = wave & 1;

  const unsigned short* qbase = qk + (size_t)(b * 2048 + qtile * 128) * 4096 + h * 128;
  const unsigned short* kbase = qk + (size_t)(b * 2048) * 4096 + 2048 + h * 128;

  bf16x8 qv[4][4];
  #pragma unroll
  for (int i = 0; i < 4; ++i) {
    int row = wr * 64 + i * 16 + (lane & 15);
    const unsigned short* qr = qbase + (size_t)row * 4096 + (lane >> 4) * 8;
    #pragma unroll
    for (int ks = 0; ks < 4; ++ks)
      qv[i][ks] = *(const bf16x8*)(qr + ks * 32);
  }

  auto stageK = [&](int bi, int kt) {
    const unsigned short* kb = kbase + (size_t)kt * 128 * 4096;
    #pragma unroll
    for (int j = 0; j < 8; ++j) {
      int base = (wave * 8 + j) * 1024;
      int o = base + lane * 16;
      int row = o >> 8;
      int c = o & 255;
      int csrc = c ^ ((row & 7) << 4);
      const char* gk = (const char*)(kb + (size_t)row * 4096) + csrc;
      __builtin_amdgcn_global_load_lds(AS_GLOBAL(gk), AS_LDS((char*)Ks[bi] + base), 16, 0, 0);
    }
  };

  float* obase = out2 + ((size_t)(b * 2048 + qtile * 128) * 16 + h) * 2048;
  const size_t qstride = (size_t)16 * 2048;

  #pragma unroll 1
  for (int rep = 0; rep < SCORES_REPS; ++rep) {
    stageK(0, 0);
    __syncthreads();

    int cur = 0;
    for (int kt = 0; kt < 16; ++kt) {
      if (kt + 1 < 16) stageK(cur ^ 1, kt + 1);

      f32x4 acc[4][4] = {};
      #pragma unroll
      for (int ks = 0; ks < 4; ++ks) {
        bf16x8 bv[4];
        const int kbyte = ks * 64 + (lane >> 4) * 16;
        #pragma unroll
        for (int j = 0; j < 4; ++j) {
          int row = wc * 64 + j * 16 + (lane & 15);
          int off = row * 256 + (kbyte ^ ((row & 7) << 4));
          bv[j] = *(const bf16x8*)((const char*)Ks[cur] + off);
        }
        #pragma unroll
        for (int i = 0; i < 4; ++i)
          #pragma unroll
          for (int j = 0; j < 4; ++j)
            acc[i][j] = __builtin_amdgcn_mfma_f32_16x16x32_bf16(qv[i][ks], bv[j], acc[i][j], 0, 0, 0);
      }

      __syncthreads();

      #pragma unroll
      for (int i = 0; i < 4; ++i)
        #pragma unroll
        for (int j = 0; j < 4; ++j)
          #pragma unroll
          for (int r = 0; r < 4; ++r) {
            int qrow = wr * 64 + i * 16 + (lane >> 4) * 4 + r;
            int col = kt * 128 + wc * 64 + j * 16 + (lane & 15);
            obase[(size_t)qrow * qstride + col] = acc[i][j][r];
          }

      cur ^= 1;
    }
    __syncthreads();   // rep boundary: buf reads all behind barriers
  }
}

extern "C" void kernel_launch(void* const* d_in, const int* in_sizes, int n_in,
                              void* d_out, int out_size, void* d_ws, size_t ws_size,
                              hipStream_t stream) {
  const float* x  = (const float*)d_in[0];
  const float* Wq = (const float*)d_in[1];
  const float* Wk = (const float*)d_in[2];
  // d_in[3] = Wv: computed then discarded by the reference -> skipped entirely.

  float* out = (float*)d_out;                             // fp32 output
  unsigned short* xb = (unsigned short*)d_ws;             // x as bf16      [4096][2048]
  unsigned short* wb = xb + (size_t)4096 * 2048;          // [Wq*scale; Wk] [4096][2048]
  unsigned short* qkbuf = wb + (size_t)4096 * 2048;       // Q||K           [4096][4096]

  const float scale = 1.0f / sqrtf(128.0f);

  // Output 0: attn_output = zeros, fp32, 2*2048*2048 elements (33.5 MB)
  hipMemsetAsync(d_out, 0, (size_t)2 * 2048 * 2048 * sizeof(float), stream);

  cvt3_kernel<<<2048, 256, 0, stream>>>(x, Wq, Wk, (ushort4*)xb, (ushort4*)wb, scale);

  proj_gemm<<<dim3(PN / 256, PM / 256), 512, 0, stream>>>(xb, wb, qkbuf);

  // Output 1: attn_weights fp32 at element offset 2*2048*2048
  scores_kernel<<<dim3(16, 32), 256, 0, stream>>>(qkbuf, out + (size_t)2 * 2048 * 2048);
}

// Round 10
// 223.694 us; speedup vs baseline: 5.3683x; 5.3683x over previous
//
#include <hip/hip_runtime.h>
#include <hip/hip_bf16.h>
#include <cstdint>
#include <cmath>

typedef __bf16 bf16_t;
typedef __attribute__((ext_vector_type(8))) bf16_t bf16x8;
typedef __attribute__((ext_vector_type(4))) float f32x4;

#define AS_GLOBAL(p) ((const __attribute__((address_space(1))) void*)(p))
#define AS_LDS(p)    ((__attribute__((address_space(3))) void*)(p))

// fp32 -> bf16 RTNE
__device__ __forceinline__ unsigned short f2bf(float f) {
  unsigned u = __builtin_bit_cast(unsigned, f);
  u += 0x7FFFu + ((u >> 16) & 1u);
  return (unsigned short)(u >> 16);
}

// ---------------- fused convert fp32 -> bf16 (x4 vectorized) ----------------
#define N4_X  2097152
#define N4_W  1048576
__global__ void cvt3_kernel(const float* __restrict__ x, const float* __restrict__ wq,
                            const float* __restrict__ wk, ushort4* __restrict__ xb4,
                            ushort4* __restrict__ wb4, float scale) {
  int i = blockIdx.x * blockDim.x + threadIdx.x;
  int stride = gridDim.x * blockDim.x;
  for (; i < N4_X + 2 * N4_W; i += stride) {
    const float4* src;
    ushort4* dst;
    float sc = 1.0f;
    if (i < N4_X) {
      src = reinterpret_cast<const float4*>(x) + i;
      dst = xb4 + i;
    } else if (i < N4_X + N4_W) {
      src = reinterpret_cast<const float4*>(wq) + (i - N4_X);
      dst = wb4 + (i - N4_X);
      sc = scale;
    } else {
      src = reinterpret_cast<const float4*>(wk) + (i - N4_X - N4_W);
      dst = wb4 + (i - N4_X);
    }
    float4 v = *src;
    ushort4 o;
    o.x = f2bf(v.x * sc);
    o.y = f2bf(v.y * sc);
    o.z = f2bf(v.z * sc);
    o.w = f2bf(v.w * sc);
    *dst = o;
  }
}

// ================= projection GEMM: 256x256 tile, 8-phase, read-once fragments =================
// R9 change vs R6: each K-tile's LDS subtiles are ds_read ONCE and kept in
// registers across quadrant phases (48 -> 24 ds_read_b128 per wave per tile).
// Q0 reads av0+bv0, Q1 reads bv1, Q2 reads av1, Q3 reads nothing.
// vmcnt ledger (re-derived for read-at-phase-top): steady {Q0:6, Q3:8},
// tail T=30 {6,-,-,4}, T=31 {0,-,-,-}.
#define PM 4096
#define PN 4096
#define PK 2048
#define PNT 32   // K tiles

template<int VM> __device__ __forceinline__ void waitcnt_vm() {
  if constexpr (VM == 0)  asm volatile("s_waitcnt vmcnt(0)" ::: "memory");
  else if constexpr (VM == 4)  asm volatile("s_waitcnt vmcnt(4)" ::: "memory");
  else if constexpr (VM == 6)  asm volatile("s_waitcnt vmcnt(6)" ::: "memory");
  else if constexpr (VM == 8)  asm volatile("s_waitcnt vmcnt(8)" ::: "memory");
  // VM < 0: no wait
}

// stage one 128x64 half-tile (16 KB): 2 x global_load_lds(16B) per thread
__device__ __forceinline__ void stage_half(const unsigned short* A, const unsigned short* B,
                                           int m0, int n0, int H, int wave, int lane,
                                           char* lds) {
  int tile = H >> 2;
  int mat  = H & 1;          // 0=A, 1=B
  int half = (H >> 1) & 1;
  int buf  = tile & 1;
  const unsigned short* src = mat ? B : A;
  int base0 = mat ? n0 : m0;
  char* hbase = lds + (((buf * 2 + mat) * 2 + half) * 16384);
  #pragma unroll
  for (int l = 0; l < 2; ++l) {
    int o = l * 8192 + wave * 1024 + lane * 16;
    int row = o >> 7;                  // 128B rows (BK=64 bf16)
    int c = o & 127;
    int csrc = c ^ ((row & 7) << 4);   // pre-swizzled global source
    const char* g = (const char*)(src + (size_t)(base0 + half * 128 + row) * PK)
                    + tile * 128 + csrc;
    __builtin_amdgcn_global_load_lds(AS_GLOBAL(g), AS_LDS(hbase + l * 8192 + wave * 1024),
                                     16, 0, 0);
  }
}

template<int Q, int VM>
__device__ __forceinline__ void phase(const unsigned short* A, const unsigned short* B,
                                      int m0, int n0, int T, int wave, int lane,
                                      int wm, int wn, char* lds, f32x4 (&acc)[8][4],
                                      bf16x8 (&av0)[4][2], bf16x8 (&av1)[4][2],
                                      bf16x8 (&bv0)[2][2], bf16x8 (&bv1)[2][2]) {
  constexpr int gm = Q >> 1, gn = Q & 1;
  const int buf = T & 1;
  const char* Ab = lds + (((buf * 2 + 0) * 2 + gm) * 16384);
  const char* Bb = lds + (((buf * 2 + 1) * 2 + gn) * 16384);

  bf16x8 (&av)[4][2] = (gm == 0) ? av0 : av1;
  bf16x8 (&bv)[2][2] = (gn == 0) ? bv0 : bv1;

  if constexpr (Q == 0 || Q == 2) {      // read this A-half once (8 x ds_read_b128)
    #pragma unroll
    for (int j = 0; j < 4; ++j) {
      int row = j * 32 + wm * 16 + (lane & 15);
      #pragma unroll
      for (int ks = 0; ks < 2; ++ks) {
        int kb = ks * 64 + (lane >> 4) * 16;
        av[j][ks] = *(const bf16x8*)(Ab + row * 128 + (kb ^ ((row & 7) << 4)));
      }
    }
  }
  if constexpr (Q == 0 || Q == 1) {      // read this B-half once (4 x ds_read_b128)
    #pragma unroll
    for (int i = 0; i < 2; ++i) {
      int row = i * 64 + wn * 16 + (lane & 15);
      #pragma unroll
      for (int ks = 0; ks < 2; ++ks) {
        int kb = ks * 64 + (lane >> 4) * 16;
        bv[i][ks] = *(const bf16x8*)(Bb + row * 128 + (kb ^ ((row & 7) << 4)));
      }
    }
  }

  int H = 4 * T + Q + 6;
  if (H < 4 * PNT) stage_half(A, B, m0, n0, H, wave, lane, lds);

  waitcnt_vm<VM>();
  asm volatile("s_barrier" ::: "memory");
  asm volatile("s_waitcnt lgkmcnt(0)" ::: "memory");
  __builtin_amdgcn_sched_barrier(0);

  __builtin_amdgcn_s_setprio(1);
  #pragma unroll
  for (int j = 0; j < 4; ++j)
    #pragma unroll
    for (int i = 0; i < 2; ++i)
      #pragma unroll
      for (int ks = 0; ks < 2; ++ks)
        acc[gm * 4 + j][gn * 2 + i] =
          __builtin_amdgcn_mfma_f32_16x16x32_bf16(av[j][ks], bv[i][ks],
                                                  acc[gm * 4 + j][gn * 2 + i], 0, 0, 0);
  __builtin_amdgcn_s_setprio(0);
  asm volatile("s_barrier" ::: "memory");
}

__global__ __launch_bounds__(512, 2) void proj_gemm(const unsigned short* __restrict__ A,
                                                    const unsigned short* __restrict__ Bm,
                                                    unsigned short* __restrict__ C) {
  __shared__ __align__(16) char lds[131072];
  const int tid = threadIdx.x;
  const int wave = tid >> 6, lane = tid & 63;
  const int wm = wave >> 2, wn = wave & 3;
  const int m0 = blockIdx.y * 256;
  const int n0 = blockIdx.x * 256;

  f32x4 acc[8][4] = {};
  bf16x8 av0[4][2], av1[4][2], bv0[2][2], bv1[2][2];

  #pragma unroll
  for (int h = 0; h < 6; ++h) stage_half(A, Bm, m0, n0, h, wave, lane, lds);
  waitcnt_vm<8>();
  asm volatile("s_barrier" ::: "memory");

  for (int T = 0; T < PNT - 2; ++T) {
    phase<0, 6>(A, Bm, m0, n0, T, wave, lane, wm, wn, lds, acc, av0, av1, bv0, bv1);
    phase<1, -1>(A, Bm, m0, n0, T, wave, lane, wm, wn, lds, acc, av0, av1, bv0, bv1);
    phase<2, -1>(A, Bm, m0, n0, T, wave, lane, wm, wn, lds, acc, av0, av1, bv0, bv1);
    phase<3, 8>(A, Bm, m0, n0, T, wave, lane, wm, wn, lds, acc, av0, av1, bv0, bv1);
  }
  phase<0, 6>(A, Bm, m0, n0, PNT - 2, wave, lane, wm, wn, lds, acc, av0, av1, bv0, bv1);
  phase<1, -1>(A, Bm, m0, n0, PNT - 2, wave, lane, wm, wn, lds, acc, av0, av1, bv0, bv1);
  phase<2, -1>(A, Bm, m0, n0, PNT - 2, wave, lane, wm, wn, lds, acc, av0, av1, bv0, bv1);
  phase<3, 4>(A, Bm, m0, n0, PNT - 2, wave, lane, wm, wn, lds, acc, av0, av1, bv0, bv1);
  phase<0, 0>(A, Bm, m0, n0, PNT - 1, wave, lane, wm, wn, lds, acc, av0, av1, bv0, bv1);
  phase<1, -1>(A, Bm, m0, n0, PNT - 1, wave, lane, wm, wn, lds, acc, av0, av1, bv0, bv1);
  phase<2, -1>(A, Bm, m0, n0, PNT - 1, wave, lane, wm, wn, lds, acc, av0, av1, bv0, bv1);
  phase<3, -1>(A, Bm, m0, n0, PNT - 1, wave, lane, wm, wn, lds, acc, av0, av1, bv0, bv1);

  #pragma unroll
  for (int f = 0; f < 8; ++f) {
    int rbase = m0 + (f >> 2) * 128 + (f & 3) * 32 + wm * 16 + (lane >> 4) * 4;
    #pragma unroll
    for (int nf = 0; nf < 4; ++nf) {
      int col = n0 + (nf >> 1) * 128 + (nf & 1) * 64 + wn * 16 + (lane & 15);
      #pragma unroll
      for (int r = 0; r < 4; ++r)
        C[(size_t)(rbase + r) * PN + col] = f2bf(acc[f][nf][r]);
    }
  }
}

// ---------------- scores kernel (R6-proven 128x128): persistent-Q, streaming-K ----------------
__global__ __launch_bounds__(256) void scores_kernel(const unsigned short* __restrict__ qk,
                                                     float* __restrict__ out2) {
  __shared__ unsigned short Ks[2][128 * 128];
  const int tid = threadIdx.x;
  const int wave = tid >> 6, lane = tid & 63;
  const int qtile = blockIdx.x;
  const int bh = blockIdx.y;
  const int b = bh >> 4, h = bh & 15;
  const int wr = wave >> 1, wc = wave & 1;

  const unsigned short* qbase = qk + (size_t)(b * 2048 + qtile * 128) * 4096 + h * 128;
  const unsigned short* kbase = qk + (size_t)(b * 2048) * 4096 + 2048 + h * 128;

  bf16x8 qv[4][4];
  #pragma unroll
  for (int i = 0; i < 4; ++i) {
    int row = wr * 64 + i * 16 + (lane & 15);
    const unsigned short* qr = qbase + (size_t)row * 4096 + (lane >> 4) * 8;
    #pragma unroll
    for (int ks = 0; ks < 4; ++ks)
      qv[i][ks] = *(const bf16x8*)(qr + ks * 32);
  }

  auto stageK = [&](int bi, int kt) {
    const unsigned short* kb = kbase + (size_t)kt * 128 * 4096;
    #pragma unroll
    for (int j = 0; j < 8; ++j) {
      int base = (wave * 8 + j) * 1024;
      int o = base + lane * 16;
      int row = o >> 8;
      int c = o & 255;
      int csrc = c ^ ((row & 7) << 4);
      const char* gk = (const char*)(kb + (size_t)row * 4096) + csrc;
      __builtin_amdgcn_global_load_lds(AS_GLOBAL(gk), AS_LDS((char*)Ks[bi] + base), 16, 0, 0);
    }
  };

  float* obase = out2 + ((size_t)(b * 2048 + qtile * 128) * 16 + h) * 2048;
  const size_t qstride = (size_t)16 * 2048;

  stageK(0, 0);
  __syncthreads();

  int cur = 0;
  for (int kt = 0; kt < 16; ++kt) {
    if (kt + 1 < 16) stageK(cur ^ 1, kt + 1);

    f32x4 acc[4][4] = {};
    #pragma unroll
    for (int ks = 0; ks < 4; ++ks) {
      bf16x8 bv[4];
      const int kbyte = ks * 64 + (lane >> 4) * 16;
      #pragma unroll
      for (int j = 0; j < 4; ++j) {
        int row = wc * 64 + j * 16 + (lane & 15);
        int off = row * 256 + (kbyte ^ ((row & 7) << 4));
        bv[j] = *(const bf16x8*)((const char*)Ks[cur] + off);
      }
      #pragma unroll
      for (int i = 0; i < 4; ++i)
        #pragma unroll
        for (int j = 0; j < 4; ++j)
          acc[i][j] = __builtin_amdgcn_mfma_f32_16x16x32_bf16(qv[i][ks], bv[j], acc[i][j], 0, 0, 0);
    }

    __syncthreads();

    #pragma unroll
    for (int i = 0; i < 4; ++i)
      #pragma unroll
      for (int j = 0; j < 4; ++j)
        #pragma unroll
        for (int r = 0; r < 4; ++r) {
          int qrow = wr * 64 + i * 16 + (lane >> 4) * 4 + r;
          int col = kt * 128 + wc * 64 + j * 16 + (lane & 15);
          obase[(size_t)qrow * qstride + col] = acc[i][j][r];
        }

    cur ^= 1;
  }
}

extern "C" void kernel_launch(void* const* d_in, const int* in_sizes, int n_in,
                              void* d_out, int out_size, void* d_ws, size_t ws_size,
                              hipStream_t stream) {
  const float* x  = (const float*)d_in[0];
  const float* Wq = (const float*)d_in[1];
  const float* Wk = (const float*)d_in[2];
  // d_in[3] = Wv: computed then discarded by the reference -> skipped entirely.

  float* out = (float*)d_out;                             // fp32 output
  unsigned short* xb = (unsigned short*)d_ws;             // x as bf16      [4096][2048]
  unsigned short* wb = xb + (size_t)4096 * 2048;          // [Wq*scale; Wk] [4096][2048]
  unsigned short* qkbuf = wb + (size_t)4096 * 2048;       // Q||K           [4096][4096]

  const float scale = 1.0f / sqrtf(128.0f);

  // Output 0: attn_output = zeros, fp32, 2*2048*2048 elements (33.5 MB)
  hipMemsetAsync(d_out, 0, (size_t)2 * 2048 * 2048 * sizeof(float), stream);

  cvt3_kernel<<<2048, 256, 0, stream>>>(x, Wq, Wk, (ushort4*)xb, (ushort4*)wb, scale);

  proj_gemm<<<dim3(PN / 256, PM / 256), 512, 0, stream>>>(xb, wb, qkbuf);

  // Output 1: attn_weights fp32 at element offset 2*2048*2048
  scores_kernel<<<dim3(16, 32), 256, 0, stream>>>(qkbuf, out + (size_t)2 * 2048 * 2048);
}